// Round 9
// baseline (155.855 us; speedup 1.0000x reference)
//
#include <hip/hip_runtime.h>
#include <stdint.h>

#pragma clang fp contract(off)

typedef unsigned long long ull;

#define HIGHT 0.7f
#define LOWT  0.3f
#define KSEL  128
#define CAP   2048         // candidate buffer per mode
#define MAXGT 512
#define TPB   256
#define CHUNK 32           // proposals per fused_iou block (8 threads/proposal)
#define TJ    128          // j-tile for the shared IoU matrix
#define SMP   132          // pitch%32==4: write bank 4pi+q+8s (2-way), read bank 4s+jloc (free)
#define NLAD  7
#define NRB   96           // colfix blocks (96 atomics/colmax address, fire-and-forget)
#define SLOTS (CAP / TPB)  // 8 rank-select slots per thread

// counter layout (int cnts[32]):
// [0] posMask  [1] negMask(normal)  [2] notPos
// [3..9] pos ladder  [10..16] neg-normal ladder  [17..23] neg-fallback ladder
// [24] collect cnt pos  [25] collect cnt neg  [26] colfix ticket  [27] collect ticket
__device__ __constant__ float LADV[NLAD] = {0.998f, 0.99f, 0.95f, 0.8f, 0.5f, 0.25f, 0.0625f};

// ---- bit-exact IoU (numpy fp32 op-for-op; no contraction; IEEE div) ----
__device__ __forceinline__ float iou_pair(float ax0, float ay0, float ax1, float ay1, float aarea,
                                          float bx0, float by0, float bx1, float by1, float barea){
#pragma clang fp contract(off)
  float x0 = fmaxf(ax0, bx0);
  float y0 = fmaxf(ay0, by0);
  float x1 = fminf(ax1, bx1);
  float y1 = fminf(ay1, by1);
  float dx = fmaxf(x1 - x0, 0.0f);
  float dy = fmaxf(y1 - y0, 0.0f);
  float inter = dx * dy;
  float uni = (aarea + barea) - inter;
  return inter / uni;   // keep IEEE div: surrogate compares flip near-tie argmax
}

// ---- K1 (R4-exact, proven 41.5us): zero forced/cnts/colmax + row max/argmax +
// LDS-tile col partials + provisional counts. 256t / CHUNK=32 is the measured
// local optimum (R7 512t: slower; R8 dual-proposal: slower).
__global__ __launch_bounds__(TPB)
void fused_iou(const float4* __restrict__ boxes, const float4* __restrict__ gts,
               int n1, int n2, int nblk,
               float* __restrict__ max_iou, int* __restrict__ input_idx,
               ull* __restrict__ colpart, int* __restrict__ forced,
               int* __restrict__ cnts_part, int* __restrict__ cnts,
               ull* __restrict__ colmax,
               const float* __restrict__ pn, const float* __restrict__ nn)
{
#pragma clang fp contract(off)
  const int b = blockIdx.x, t = threadIdx.x;

  // distributed zeroing (consumed by later kernels; stream order suffices).
  // NOTE: colmax/cnts MUST be re-zeroed every launch — the harness re-poisons
  // the workspace between runs and colfix atomicMax's into colmax (R6 failure:
  // the colmax zero was dropped and poison keys won the max).
  for (int x = b * TPB + t; x < n1; x += nblk * TPB) forced[x] = 0;
  if (b == 0){
    if (t < 32) cnts[t] = 0;
    for (int x = t; x < n2; x += TPB) colmax[x] = 0;  // key 0 loses to any real key
  }

  __shared__ float4 gc[MAXGT];
  __shared__ float  ga[MAXGT];
  __shared__ float  smat[CHUNK * SMP];   // 32 x 132 fp32 = 16.9 KB
  __shared__ float  sm[CHUNK];

  for (int j = t; j < n2; j += TPB){
    float4 g = gts[j];
    float hw = g.z * 0.5f, hh = g.w * 0.5f;
    gc[j] = make_float4(g.x - hw, g.y - hh, g.x + hw, g.y + hh);
    ga[j] = g.z * g.w;
  }
  __syncthreads();

  const int lo = b * CHUNK;
  int cr = n1 - lo; if (cr > CHUNK) cr = CHUNK; if (cr < 0) cr = 0;

  const int pi = t >> 3, q = t & 7;      // 8 threads per proposal
  const bool valid = (pi < cr);
  float px0 = 0, py0 = 0, px1 = 0, py1 = 0, pa = 0;
  if (valid){
    float4 pb = boxes[lo + pi];
    float hw = pb.z * 0.5f, hh = pb.w * 0.5f;
    px0 = pb.x - hw; py0 = pb.y - hh; px1 = pb.x + hw; py1 = pb.y + hh;
    pa = pb.z * pb.w;
  }
  // 4 independent row-argmax chains (disjoint j-sets; merged lexicographically)
  float vA = -1.0f, vB = -1.0f, vC = -1.0f, vD = -1.0f;
  int jA = 0, jB = 0, jC = 0, jD = 0;

  for (int tb = 0; tb < n2; tb += TJ){
    const int tn = min(TJ, n2 - tb);
    // row compute: octant q covers j = tb+q+8s; each IoU stored once in smat.
    // FOUR independent chains overlap the fp32-div latency.
    // smat write bank: (4pi + q + 8s)%32 -> worst 2-way (free).
    if (valid){
      const int jlim = tb + tn;
      int j0 = tb + q;
      for (; j0 + 24 < jlim; j0 += 32){
        const int ja = j0, jb = j0 + 8, jc = j0 + 16, jd = j0 + 24;
        float4 gA = gc[ja]; float aA = ga[ja];
        float4 gB = gc[jb]; float aB = ga[jb];
        float4 gC = gc[jc]; float aC = ga[jc];
        float4 gD = gc[jd]; float aD = ga[jd];
        float u = iou_pair(px0, py0, px1, py1, pa, gA.x, gA.y, gA.z, gA.w, aA);
        float v = iou_pair(px0, py0, px1, py1, pa, gB.x, gB.y, gB.z, gB.w, aB);
        float w = iou_pair(px0, py0, px1, py1, pa, gC.x, gC.y, gC.z, gC.w, aC);
        float x = iou_pair(px0, py0, px1, py1, pa, gD.x, gD.y, gD.z, gD.w, aD);
        smat[pi * SMP + (ja - tb)] = u;
        smat[pi * SMP + (jb - tb)] = v;
        smat[pi * SMP + (jc - tb)] = w;
        smat[pi * SMP + (jd - tb)] = x;
        if (u > vA){ vA = u; jA = ja; }
        if (v > vB){ vB = v; jB = jb; }
        if (w > vC){ vC = w; jC = jc; }
        if (x > vD){ vD = x; jD = jd; }
      }
      for (; j0 < jlim; j0 += 8){
        float4 g0 = gc[j0]; float a0 = ga[j0];
        float u = iou_pair(px0, py0, px1, py1, pa, g0.x, g0.y, g0.z, g0.w, a0);
        smat[pi * SMP + (j0 - tb)] = u;
        if (u > vA){ vA = u; jA = j0; }
      }
    }
    __syncthreads();
    // col reduce: 2 threads/j, blocked p-chains of 16 (disjoint ascending ->
    // merge lower-p on tie = global first occurrence). Read bank:
    // (4s + jloc)%32 across a wave -> conflict-free. Row-major colpart write
    // is coalesced (4KB/block contiguous).
    {
      const int jloc = t >> 1, half = t & 1;
      if (jloc < tn){
        float cv = -1.0f; int cp = 0;
        const int p0 = half * 16;
        const int p1 = min(p0 + 16, cr);
        for (int p = p0; p < p1; ++p){
          float v = smat[p * SMP + jloc];
          if (v > cv){ cv = v; cp = p; }
        }
        float ov = __shfl_xor(cv, 1, 64);
        int   op = __shfl_xor(cp, 1, 64);
        if (ov > cv || (ov == cv && op < cp)){ cv = ov; cp = op; }
        if (half == 0){
          // key: bits(nonneg IoU)<<32 | ~globalIdx -> max = best val, tie lowest idx
          colpart[(size_t)b * n2 + (tb + jloc)] =
            ((ull)__float_as_uint(cv) << 32) | (ull)(unsigned)~(unsigned)(lo + cp);
        }
      }
    }
    __syncthreads();
  }

  // merge the 4 chains (disjoint j-sets -> lexicographic merge is exact)
  if (vB > vA || (vB == vA && jB < jA)){ vA = vB; jA = jB; }
  if (vC > vA || (vC == vA && jC < jA)){ vA = vC; jA = jC; }
  if (vD > vA || (vD == vA && jD < jA)){ vA = vD; jA = jD; }
  // merge the 8 octants of the row argmax (tie -> lower j)
  #pragma unroll
  for (int m = 1; m <= 4; m <<= 1){
    float ov = __shfl_xor(vA, m, 64);
    int   oj = __shfl_xor(jA, m, 64);
    if (ov > vA || (ov == vA && oj < jA)){ vA = ov; jA = oj; }
  }
  if (valid && q == 0){
    max_iou[lo + pi] = vA;
    input_idx[lo + pi] = jA;
    sm[pi] = vA;
  }
  __syncthreads();

  // provisional counts (ignore forced; colfix corrects): wave 0, lane t = proposal
  if (t < 64){
    const bool vld = (t < cr);
    float m = vld ? sm[t] : -1.0f;
    bool pos = vld && (m > HIGHT);
    bool nm  = vld && (m < LOWT);
    bool np  = vld && !(m > HIGHT);
    float sp = pos ? pn[lo + t] : -1.0f;
    float sn = (nm || np) ? nn[lo + t] : -1.0f;
    int c[24];
    c[0] = __popcll(__ballot(pos));
    c[1] = __popcll(__ballot(nm));
    c[2] = __popcll(__ballot(np));
    #pragma unroll
    for (int k = 0; k < NLAD; ++k){
      float L = LADV[k];
      c[3 + k]  = __popcll(__ballot(pos && sp > L));
      c[10 + k] = __popcll(__ballot(nm  && sn > L));
      c[17 + k] = __popcll(__ballot(np  && sn > L));
    }
    if (t == 0){
      #pragma unroll
      for (int k = 0; k < 24; ++k) cnts_part[b * 24 + k] = c[k];
    }
  }
}

// ---- K2 (R8-proven): fence-light column reduction + last-block ticketed forcefix.
// Phase A: thread t owns columns t and t+256; each block scans rows b, b+NRB, ...
// reading full 4KB rows coalesced; one fire-and-forget atomicMax per column per
// block. Then ONE fence + ticket; only the last-arriving block runs forcefix
// (AGENT loads of colmax); all others exit. No spinning (R3 lesson).
__global__ __launch_bounds__(TPB)
void colfix(const ull* __restrict__ colpart, int n1, int n2, int nblk,
            const float* __restrict__ max_iou,
            const float* __restrict__ pn, const float* __restrict__ nn,
            int* __restrict__ forced, const int* __restrict__ cnts_part,
            int* __restrict__ cnts, ull* __restrict__ colmax)
{
  const int t = threadIdx.x, b = blockIdx.x;
  ull m0 = 0, m1 = 0;
  const int c0 = t, c1 = t + TPB;          // n2 = 512 = 2*TPB
  for (int x = b; x < nblk; x += NRB){
    const ull* row = colpart + (size_t)x * n2;
    ull v0 = row[c0];
    ull v1 = (c1 < n2) ? row[c1] : 0;
    if (v0 > m0) m0 = v0;
    if (v1 > m1) m1 = v1;
  }
  if (c0 < n2 && m0) atomicMax(&colmax[c0], m0);
  if (c1 < n2 && m1) atomicMax(&colmax[c1], m1);

  // provisional counter reduction (24 columns); corrections below are
  // commutative atomicAdds so ordering vs these is irrelevant.
  if (t < 24){
    int s = 0;
    for (int x = b; x < nblk; x += NRB) s += cnts_part[x * 24 + t];
    if (s) atomicAdd(&cnts[t], s);
  }

  __threadfence();
  __syncthreads();                         // all this block's atomics acked
  __shared__ int islast;
  if (t == 0) islast = (atomicAdd(&cnts[26], 1) == NRB - 1) ? 1 : 0;
  __syncthreads();
  if (!islast) return;

  // last block: every other block's atomicMax completed before its ticket ->
  // colmax at LLC is final. AGENT loads bypass possibly-stale local caches.
  for (int j = t; j < n2; j += TPB){
    ull key = __hip_atomic_load(&colmax[j], __ATOMIC_RELAXED, __HIP_MEMORY_SCOPE_AGENT);
    unsigned idx = ~(unsigned)(key & 0xFFFFFFFFull);
    if (idx < (unsigned)n1){
      int old = atomicExch(&forced[idx], 1);    // dedupe: first claimer corrects
      if (old == 0){
        float m2 = max_iou[idx];
        if (!(m2 > HIGHT)){                     // forcing flips this row to pos
          float sp = pn[idx];
          float sn = nn[idx];
          atomicAdd(&cnts[0], 1);
          atomicAdd(&cnts[2], -1);
          #pragma unroll
          for (int k = 0; k < NLAD; ++k){
            float L = LADV[k];
            if (sp > L) atomicAdd(&cnts[3 + k], 1);
            if (sn > L) atomicAdd(&cnts[17 + k], -1);
          }
          if (m2 < LOWT){
            atomicAdd(&cnts[1], -1);
            #pragma unroll
            for (int k = 0; k < NLAD; ++k)
              if (sn > LADV[k]) atomicAdd(&cnts[10 + k], -1);
          }
        }
      }
    }
  }
}

// ---- tau: LARGEST ladder level with >= KSEL survivors (tight superset).
// Exact: the top-KSEL by noise all score > that level; adjacent ladder
// fractions differ <=5x so survivors at the chosen level stay << CAP.
// If no level qualifies (totM < ~KSEL) tau=-1 collects all masked.
__device__ __forceinline__ float pick_tau2(const int* lad){
  for (int k = 0; k < NLAD; ++k)
    if (lad[k] >= KSEL) return LADV[k];
  return -1.0f;
}

// ---- K3: grid-wide collect into global cand buffers + last-block ticketed
// rank-select for both modes (same ticket pattern as colfix — no spinning;
// last-arriving block does the select after a release/acquire fence pair).
__global__ __launch_bounds__(TPB)
void collect_select(const float* __restrict__ max_iou, const int* __restrict__ forced,
                    const float* __restrict__ pn, const float* __restrict__ nn,
                    int n1, int* __restrict__ cnts, ull* __restrict__ cand,
                    const int* __restrict__ input_idx, int* __restrict__ out)
{
  __shared__ int s_c[24];
  const int t = threadIdx.x;
  if (t < 24) s_c[t] = cnts[t];
  __syncthreads();
  const bool fb = (s_c[1] == 0);                 // no negatives -> complement of pos
  const int totP = s_c[0];
  const int totN = fb ? s_c[2] : s_c[1];
  const float tauP = pick_tau2(&s_c[3]);
  const float tauN = pick_tau2(fb ? &s_c[17] : &s_c[10]);

  const int i = blockIdx.x * TPB + t;
  if (i < n1){
    float m = max_iou[i];
    bool f = forced[i] != 0;
    bool pos = (m > HIGHT) || f;
    // Key: (bits(score)+1)<<32 | ~i (score in [0,1) -> bits monotone; +1 so the
    // fill key (k32=0) loses to a real 0.0 score; ~i -> tie picks lowest index,
    // fill keys order ascending-index, matching ref top_k).
    if (pos){
      float sc = pn[i];
      if (sc > tauP){
        int p = atomicAdd(&cnts[24], 1);
        if (p < CAP) cand[p] = ((ull)(__float_as_uint(sc) + 1u) << 32) | (ull)(unsigned)~(unsigned)i;
      }
    } else if (totP < KSEL && i < 2 * KSEL){
      // ref top_k fills with -1-scored entries in ascending index; all needed
      // fills have index < 2*KSEL
      int p = atomicAdd(&cnts[24], 1);
      if (p < CAP) cand[p] = (ull)(unsigned)~(unsigned)i;
    }
    bool seln = fb ? (!pos) : ((m < LOWT) && !f);
    if (seln){
      float sc = nn[i];
      if (sc > tauN){
        int p = atomicAdd(&cnts[25], 1);
        if (p < CAP) cand[CAP + p] = ((ull)(__float_as_uint(sc) + 1u) << 32) | (ull)(unsigned)~(unsigned)i;
      }
    } else if (totN < KSEL && i < 2 * KSEL){
      int p = atomicAdd(&cnts[25], 1);
      if (p < CAP) cand[CAP + p] = (ull)(unsigned)~(unsigned)i;
    }
  }

  // ---- ticket: last-arriving block runs both rank-selects ----
  __threadfence();                         // release: cand stores visible before ticket
  __syncthreads();
  __shared__ int islast;
  if (t == 0) islast = (atomicAdd(&cnts[27], 1) == (int)gridDim.x - 1) ? 1 : 0;
  __syncthreads();
  if (!islast) return;
  __threadfence();                         // acquire side

  __shared__ ull keys[CAP];                // 16 KB
  for (int mode = 0; mode < 2; ++mode){
    const bool isPos = (mode == 0);
    int n = __hip_atomic_load(&cnts[isPos ? 24 : 25], __ATOMIC_RELAXED, __HIP_MEMORY_SCOPE_AGENT);
    if (n > CAP) n = CAP;
    for (int x = t; x < n; x += TPB)
      keys[x] = __hip_atomic_load(&cand[(isPos ? 0 : CAP) + x], __ATOMIC_RELAXED, __HIP_MEMORY_SCOPE_AGENT);
    __syncthreads();
    // exact rank-select of top-KSEL (keys totally ordered, unique).
    // fixed register slots (compile-time indices); sentinel ~0ull never written.
    ull mk[SLOTS]; int mr[SLOTS];
    #pragma unroll
    for (int e = 0; e < SLOTS; ++e){
      int x = t + e * TPB;
      mk[e] = (x < n) ? keys[x] : ~0ull;
      mr[e] = 0;
    }
    for (int o = 0; o < n; ++o){
      ull ko = keys[o];                    // uniform addr -> LDS broadcast
      #pragma unroll
      for (int e = 0; e < SLOTS; ++e) mr[e] += (ko > mk[e]);
    }
    #pragma unroll
    for (int e = 0; e < SLOTS; ++e){
      int x = t + e * TPB;
      if (x < n && mr[e] < KSEL){
        unsigned idx = ~(unsigned)(mk[e] & 0xFFFFFFFFull);
        if (isPos){ out[mr[e]] = (int)idx; out[KSEL + mr[e]] = input_idx[idx]; }
        else        out[2 * KSEL + mr[e]] = (int)idx;
      }
    }
    __syncthreads();                       // keys reused by the next mode
  }
}

extern "C" void kernel_launch(void* const* d_in, const int* in_sizes, int n_in,
                              void* d_out, int out_size, void* d_ws, size_t ws_size,
                              hipStream_t stream){
  const float4* boxes = (const float4*)d_in[0];
  const float4* gts   = (const float4*)d_in[1];
  const float* pos_noise = (const float*)d_in[2];
  const float* neg_noise = (const float*)d_in[3];
  const int n1 = in_sizes[0] / 4;
  const int n2 = in_sizes[1] / 4;
  int* out = (int*)d_out;

  char* ws = (char*)d_ws;
  size_t off = 0;
  auto carve = [&](size_t bytes) -> char* {
    char* p = ws + off;
    off = (off + bytes + 255) & ~(size_t)255;
    return p;
  };
  const int nblk = (n1 + CHUNK - 1) / CHUNK;       // 1563
  float* max_iou   = (float*)carve((size_t)n1 * 4);
  int*   input_idx = (int*)  carve((size_t)n1 * 4);
  ull*   colpart   = (ull*)  carve((size_t)nblk * n2 * 8);
  int*   forced    = (int*)  carve((size_t)n1 * 4);
  int*   cnts_part = (int*)  carve((size_t)nblk * 24 * 4);
  int*   cnts      = (int*)  carve(32 * 4);
  ull*   colmax    = (ull*)  carve((size_t)MAXGT * 8);
  ull*   cand      = (ull*)  carve((size_t)2 * CAP * 8);

  const int gb = (n1 + TPB - 1) / TPB;             // 196
  fused_iou<<<nblk, TPB, 0, stream>>>(boxes, gts, n1, n2, nblk,
                                      max_iou, input_idx, colpart, forced,
                                      cnts_part, cnts, colmax, pos_noise, neg_noise);
  colfix<<<NRB, TPB, 0, stream>>>(colpart, n1, n2, nblk, max_iou,
                                  pos_noise, neg_noise, forced, cnts_part, cnts, colmax);
  collect_select<<<gb, TPB, 0, stream>>>(max_iou, forced, pos_noise, neg_noise,
                                         n1, cnts, cand, input_idx, out);
}

// Round 10
// 135.010 us; speedup vs baseline: 1.1544x; 1.1544x over previous
//
#include <hip/hip_runtime.h>
#include <stdint.h>

#pragma clang fp contract(off)

typedef unsigned long long ull;

#define HIGHT 0.7f
#define LOWT  0.3f
#define KSEL  128
#define CAP   2048         // candidate keys per mode (LDS in finalize2)
#define MAXGT 512
#define TPB   256
#define TPF   1024         // finalize2 block size
#define CHUNK 32           // proposals per fused_iou block (8 threads/proposal)
#define TJ    128          // j-tile for the shared IoU matrix
#define SMP   132          // pitch%32==4: write bank 4pi+q+8s (2-way), read bank 4s+jloc (free)
#define NLAD  7
#define NRB   96           // colreduce2 blocks (96 atomics/colmax address, fire-and-forget)
#define BMW   1568         // forced-bitmap words (>= ceil(50000/32))

// counter layout (int cnts[32]):
// [0] posMask  [1] negMask(normal)  [2] notPos
// [3..9] pos ladder  [10..16] neg-normal ladder  [17..23] neg-fallback ladder
__device__ __constant__ float LADV[NLAD] = {0.998f, 0.99f, 0.95f, 0.8f, 0.5f, 0.25f, 0.0625f};

// ---- bit-exact IoU (numpy fp32 op-for-op; no contraction; IEEE div) ----
__device__ __forceinline__ float iou_pair(float ax0, float ay0, float ax1, float ay1, float aarea,
                                          float bx0, float by0, float bx1, float by1, float barea){
#pragma clang fp contract(off)
  float x0 = fmaxf(ax0, bx0);
  float y0 = fmaxf(ay0, by0);
  float x1 = fminf(ax1, bx1);
  float y1 = fminf(ay1, by1);
  float dx = fmaxf(x1 - x0, 0.0f);
  float dy = fmaxf(y1 - y0, 0.0f);
  float inter = dx * dy;
  float uni = (aarea + barea) - inter;
  return inter / uni;   // keep IEEE div: surrogate compares flip near-tie argmax
}

// ---- K1 (R4-exact, proven 41.5us; forced[] zeroing removed — buffer is gone):
// zero cnts/colmax + row max/argmax + LDS-tile col partials + provisional counts.
// 256t / CHUNK=32 is the measured local optimum (R7 512t and R8 dual-proposal
// both slower: VALU-issue-bound, not occupancy/LDS-bound).
__global__ __launch_bounds__(TPB)
void fused_iou(const float4* __restrict__ boxes, const float4* __restrict__ gts,
               int n1, int n2, int nblk,
               float* __restrict__ max_iou, int* __restrict__ input_idx,
               ull* __restrict__ colpart,
               int* __restrict__ cnts_part, int* __restrict__ cnts,
               ull* __restrict__ colmax,
               const float* __restrict__ pn, const float* __restrict__ nn)
{
#pragma clang fp contract(off)
  const int b = blockIdx.x, t = threadIdx.x;

  // zeroing of atomic targets (consumed by colreduce2; stream order suffices).
  // NOTE: colmax/cnts MUST be re-zeroed every launch — the harness re-poisons
  // the workspace between runs and colreduce2 atomicMax's into colmax (R6
  // failure: the colmax zero was dropped and poison keys won the max).
  if (b == 0){
    if (t < 32) cnts[t] = 0;
    for (int x = t; x < n2; x += TPB) colmax[x] = 0;  // key 0 loses to any real key
  }

  __shared__ float4 gc[MAXGT];
  __shared__ float  ga[MAXGT];
  __shared__ float  smat[CHUNK * SMP];   // 32 x 132 fp32 = 16.9 KB
  __shared__ float  sm[CHUNK];

  for (int j = t; j < n2; j += TPB){
    float4 g = gts[j];
    float hw = g.z * 0.5f, hh = g.w * 0.5f;
    gc[j] = make_float4(g.x - hw, g.y - hh, g.x + hw, g.y + hh);
    ga[j] = g.z * g.w;
  }
  __syncthreads();

  const int lo = b * CHUNK;
  int cr = n1 - lo; if (cr > CHUNK) cr = CHUNK; if (cr < 0) cr = 0;

  const int pi = t >> 3, q = t & 7;      // 8 threads per proposal
  const bool valid = (pi < cr);
  float px0 = 0, py0 = 0, px1 = 0, py1 = 0, pa = 0;
  if (valid){
    float4 pb = boxes[lo + pi];
    float hw = pb.z * 0.5f, hh = pb.w * 0.5f;
    px0 = pb.x - hw; py0 = pb.y - hh; px1 = pb.x + hw; py1 = pb.y + hh;
    pa = pb.z * pb.w;
  }
  // 4 independent row-argmax chains (disjoint j-sets; merged lexicographically)
  float vA = -1.0f, vB = -1.0f, vC = -1.0f, vD = -1.0f;
  int jA = 0, jB = 0, jC = 0, jD = 0;

  for (int tb = 0; tb < n2; tb += TJ){
    const int tn = min(TJ, n2 - tb);
    // row compute: octant q covers j = tb+q+8s; each IoU stored once in smat.
    // FOUR independent chains overlap the fp32-div latency.
    // smat write bank: (4pi + q + 8s)%32 -> worst 2-way (free).
    if (valid){
      const int jlim = tb + tn;
      int j0 = tb + q;
      for (; j0 + 24 < jlim; j0 += 32){
        const int ja = j0, jb = j0 + 8, jc = j0 + 16, jd = j0 + 24;
        float4 gA = gc[ja]; float aA = ga[ja];
        float4 gB = gc[jb]; float aB = ga[jb];
        float4 gC = gc[jc]; float aC = ga[jc];
        float4 gD = gc[jd]; float aD = ga[jd];
        float u = iou_pair(px0, py0, px1, py1, pa, gA.x, gA.y, gA.z, gA.w, aA);
        float v = iou_pair(px0, py0, px1, py1, pa, gB.x, gB.y, gB.z, gB.w, aB);
        float w = iou_pair(px0, py0, px1, py1, pa, gC.x, gC.y, gC.z, gC.w, aC);
        float x = iou_pair(px0, py0, px1, py1, pa, gD.x, gD.y, gD.z, gD.w, aD);
        smat[pi * SMP + (ja - tb)] = u;
        smat[pi * SMP + (jb - tb)] = v;
        smat[pi * SMP + (jc - tb)] = w;
        smat[pi * SMP + (jd - tb)] = x;
        if (u > vA){ vA = u; jA = ja; }
        if (v > vB){ vB = v; jB = jb; }
        if (w > vC){ vC = w; jC = jc; }
        if (x > vD){ vD = x; jD = jd; }
      }
      for (; j0 < jlim; j0 += 8){
        float4 g0 = gc[j0]; float a0 = ga[j0];
        float u = iou_pair(px0, py0, px1, py1, pa, g0.x, g0.y, g0.z, g0.w, a0);
        smat[pi * SMP + (j0 - tb)] = u;
        if (u > vA){ vA = u; jA = j0; }
      }
    }
    __syncthreads();
    // col reduce: 2 threads/j, blocked p-chains of 16 (disjoint ascending ->
    // merge lower-p on tie = global first occurrence). Read bank:
    // (4s + jloc)%32 across a wave -> conflict-free. Row-major colpart write
    // is coalesced (4KB/block contiguous).
    {
      const int jloc = t >> 1, half = t & 1;
      if (jloc < tn){
        float cv = -1.0f; int cp = 0;
        const int p0 = half * 16;
        const int p1 = min(p0 + 16, cr);
        for (int p = p0; p < p1; ++p){
          float v = smat[p * SMP + jloc];
          if (v > cv){ cv = v; cp = p; }
        }
        float ov = __shfl_xor(cv, 1, 64);
        int   op = __shfl_xor(cp, 1, 64);
        if (ov > cv || (ov == cv && op < cp)){ cv = ov; cp = op; }
        if (half == 0){
          // key: bits(nonneg IoU)<<32 | ~globalIdx -> max = best val, tie lowest idx
          colpart[(size_t)b * n2 + (tb + jloc)] =
            ((ull)__float_as_uint(cv) << 32) | (ull)(unsigned)~(unsigned)(lo + cp);
        }
      }
    }
    __syncthreads();
  }

  // merge the 4 chains (disjoint j-sets -> lexicographic merge is exact)
  if (vB > vA || (vB == vA && jB < jA)){ vA = vB; jA = jB; }
  if (vC > vA || (vC == vA && jC < jA)){ vA = vC; jA = jC; }
  if (vD > vA || (vD == vA && jD < jA)){ vA = vD; jA = jD; }
  // merge the 8 octants of the row argmax (tie -> lower j)
  #pragma unroll
  for (int m = 1; m <= 4; m <<= 1){
    float ov = __shfl_xor(vA, m, 64);
    int   oj = __shfl_xor(jA, m, 64);
    if (ov > vA || (ov == vA && oj < jA)){ vA = ov; jA = oj; }
  }
  if (valid && q == 0){
    max_iou[lo + pi] = vA;
    input_idx[lo + pi] = jA;
    sm[pi] = vA;
  }
  __syncthreads();

  // provisional counts (ignore forced; finalize2 corrects locally): wave 0
  if (t < 64){
    const bool vld = (t < cr);
    float m = vld ? sm[t] : -1.0f;
    bool pos = vld && (m > HIGHT);
    bool nm  = vld && (m < LOWT);
    bool np  = vld && !(m > HIGHT);
    float sp = pos ? pn[lo + t] : -1.0f;
    float sn = (nm || np) ? nn[lo + t] : -1.0f;
    int c[24];
    c[0] = __popcll(__ballot(pos));
    c[1] = __popcll(__ballot(nm));
    c[2] = __popcll(__ballot(np));
    #pragma unroll
    for (int k = 0; k < NLAD; ++k){
      float L = LADV[k];
      c[3 + k]  = __popcll(__ballot(pos && sp > L));
      c[10 + k] = __popcll(__ballot(nm  && sn > L));
      c[17 + k] = __popcll(__ballot(np  && sn > L));
    }
    if (t == 0){
      #pragma unroll
      for (int k = 0; k < 24; ++k) cnts_part[b * 24 + k] = c[k];
    }
  }
}

// ---- K2 (R4-exact, proven): fence-free row-sliced column reduction + cnts
// reduce. Thread t owns columns t and t+256; each block scans rows b, b+NRB,
// ... reading full 4KB rows coalesced. One fire-and-forget atomicMax per
// column per block (NRB per address, no barrier behind them, no fences).
__global__ __launch_bounds__(TPB)
void colreduce2(const ull* __restrict__ colpart, int n2, int nblk,
                const int* __restrict__ cnts_part,
                int* __restrict__ cnts, ull* __restrict__ colmax)
{
  const int t = threadIdx.x, b = blockIdx.x;
  ull m0 = 0, m1 = 0;
  const int c0 = t, c1 = t + TPB;          // n2 = 512 = 2*TPB
  for (int x = b; x < nblk; x += NRB){
    const ull* row = colpart + (size_t)x * n2;
    ull v0 = row[c0];
    ull v1 = (c1 < n2) ? row[c1] : 0;
    if (v0 > m0) m0 = v0;
    if (v1 > m1) m1 = v1;
  }
  if (c0 < n2 && m0) atomicMax(&colmax[c0], m0);
  if (c1 < n2 && m1) atomicMax(&colmax[c1], m1);

  // provisional counter reduction (24 columns)
  if (t < 24){
    int s = 0;
    for (int x = b; x < nblk; x += NRB) s += cnts_part[x * 24 + t];
    if (s) atomicAdd(&cnts[t], s);
  }
}

// ---- tau: LARGEST ladder level with >= KSEL survivors (tight superset).
// Exact: the top-KSEL by noise all score > that level; adjacent ladder
// fractions differ <=5x so survivors at the chosen level stay << CAP.
// If no level qualifies (totM < ~KSEL) tau=-1 collects all masked.
__device__ __forceinline__ float pick_tau2(const int* lad){
  for (int k = 0; k < NLAD; ++k)
    if (lad[k] >= KSEL) return LADV[k];
  return -1.0f;
}

// ---- K3: 2 blocks (block 0 = pos, block 1 = neg), each fully independent.
// LOCAL forcefix replay: read colmax (visible via kernel boundary), build an
// LDS forced-bitmap (atomicOr dedupe) and apply counter corrections to a
// private LDS copy of cnts — both blocks deterministically compute the same
// values, so NO global forced[]/fences/tickets are needed (R9 lesson: a
// device-scope fence in a wide grid costs ~50us; here sync = kernel boundary).
// Then: tight-tau scan (float4 loads) -> LDS keys -> exact rank-select -> out.
__global__ __launch_bounds__(TPF)
void finalize2(const ull* __restrict__ colmax, int n1, int n2,
               const float* __restrict__ max_iou, const int* __restrict__ input_idx,
               const float* __restrict__ pn, const float* __restrict__ nn,
               const int* __restrict__ cnts, int* __restrict__ out)
{
  const int t = threadIdx.x;
  const bool isPos = (blockIdx.x == 0);
  __shared__ int s_c[24];
  __shared__ int bm[BMW];        // forced bitmap, 6.3 KB
  __shared__ int lcnt;
  __shared__ ull keys[CAP];      // 16 KB

  if (t < 24) s_c[t] = cnts[t];
  if (t == 0) lcnt = 0;
  for (int x = t; x < BMW; x += TPF) bm[x] = 0;
  __syncthreads();

  // forcefix replay: each GT column's winner becomes forced; first claimer
  // (within this block, via LDS atomicOr) applies the counter corrections.
  if (t < n2){
    ull key = colmax[t];
    unsigned idx = ~(unsigned)(key & 0xFFFFFFFFull);
    if (idx < (unsigned)n1){
      int old = atomicOr(&bm[idx >> 5], 1 << (idx & 31));
      if (!(old & (1 << (idx & 31)))){          // unique forced proposal
        float m2 = max_iou[idx];
        if (!(m2 > HIGHT)){                     // forcing flips this row to pos
          float sp = pn[idx];
          float sn = nn[idx];
          atomicAdd(&s_c[0], 1);
          atomicAdd(&s_c[2], -1);
          #pragma unroll
          for (int k = 0; k < NLAD; ++k){
            float L = LADV[k];
            if (sp > L) atomicAdd(&s_c[3 + k], 1);
            if (sn > L) atomicAdd(&s_c[17 + k], -1);
          }
          if (m2 < LOWT){
            atomicAdd(&s_c[1], -1);
            #pragma unroll
            for (int k = 0; k < NLAD; ++k)
              if (sn > LADV[k]) atomicAdd(&s_c[10 + k], -1);
          }
        }
      }
    }
  }
  __syncthreads();

  const bool fb = (s_c[1] == 0);                 // no negatives -> complement of pos
  const int totM = isPos ? s_c[0] : (fb ? s_c[2] : s_c[1]);
  const float tau = isPos ? pick_tau2(&s_c[3]) : pick_tau2(fb ? &s_c[17] : &s_c[10]);
  const float* noise = isPos ? pn : nn;
  const bool fillOn = (totM < KSEL);

  // Key: (bits(score)+1)<<32 | ~i (score in [0,1) -> bits monotone; +1 so the
  // fill key (k32=0) loses to a real 0.0 score; ~i -> tie picks lowest index,
  // and fill keys order by ascending index, matching ref top_k).
  const int n4 = n1 >> 2;
  for (int v = t; v < n4; v += TPF){
    const float4 m4 = reinterpret_cast<const float4*>(max_iou)[v];
    const float4 s4 = reinterpret_cast<const float4*>(noise)[v];
    #pragma unroll
    for (int e = 0; e < 4; ++e){
      const float m  = (e==0)?m4.x:(e==1)?m4.y:(e==2)?m4.z:m4.w;
      const float sc = (e==0)?s4.x:(e==1)?s4.y:(e==2)?s4.z:s4.w;
      const int i = v * 4 + e;
      const bool f = (bm[i >> 5] >> (i & 31)) & 1;
      const bool pos = (m > HIGHT) || f;
      const bool sel = isPos ? pos : (fb ? (!pos) : ((m < LOWT) && !f));
      if (sel){
        if (sc > tau){
          int p = atomicAdd(&lcnt, 1);
          if (p < CAP) keys[p] = ((ull)(__float_as_uint(sc) + 1u) << 32) | (ull)(unsigned)~(unsigned)i;
        }
      } else if (fillOn && i < 2 * KSEL){
        int p = atomicAdd(&lcnt, 1);
        if (p < CAP) keys[p] = (ull)(unsigned)~(unsigned)i;
      }
    }
  }
  for (int i = (n4 << 2) + t; i < n1; i += TPF){
    const float m = max_iou[i];
    const float sc = noise[i];
    const bool f = (bm[i >> 5] >> (i & 31)) & 1;
    const bool pos = (m > HIGHT) || f;
    const bool sel = isPos ? pos : (fb ? (!pos) : ((m < LOWT) && !f));
    if (sel){
      if (sc > tau){
        int p = atomicAdd(&lcnt, 1);
        if (p < CAP) keys[p] = ((ull)(__float_as_uint(sc) + 1u) << 32) | (ull)(unsigned)~(unsigned)i;
      }
    } else if (fillOn && i < 2 * KSEL){
      int p = atomicAdd(&lcnt, 1);
      if (p < CAP) keys[p] = (ull)(unsigned)~(unsigned)i;
    }
  }
  __syncthreads();

  // exact rank-select of top-KSEL (keys totally ordered, unique).
  // fixed register slots (compile-time indices); sentinel ~0ull never written.
  int n = lcnt; if (n > CAP) n = CAP;
  ull mk[2]; int mr[2];
  #pragma unroll
  for (int e = 0; e < 2; ++e){
    int x = t + e * TPF;
    mk[e] = (x < n) ? keys[x] : ~0ull;
    mr[e] = 0;
  }
  for (int o = 0; o < n; ++o){
    ull ko = keys[o];                    // uniform addr -> LDS broadcast
    mr[0] += (ko > mk[0]);
    mr[1] += (ko > mk[1]);
  }
  #pragma unroll
  for (int e = 0; e < 2; ++e){
    int x = t + e * TPF;
    if (x < n && mr[e] < KSEL){
      unsigned idx = ~(unsigned)(mk[e] & 0xFFFFFFFFull);
      if (isPos){ out[mr[e]] = (int)idx; out[KSEL + mr[e]] = input_idx[idx]; }
      else        out[2 * KSEL + mr[e]] = (int)idx;
    }
  }
}

extern "C" void kernel_launch(void* const* d_in, const int* in_sizes, int n_in,
                              void* d_out, int out_size, void* d_ws, size_t ws_size,
                              hipStream_t stream){
  const float4* boxes = (const float4*)d_in[0];
  const float4* gts   = (const float4*)d_in[1];
  const float* pos_noise = (const float*)d_in[2];
  const float* neg_noise = (const float*)d_in[3];
  const int n1 = in_sizes[0] / 4;
  const int n2 = in_sizes[1] / 4;
  int* out = (int*)d_out;

  char* ws = (char*)d_ws;
  size_t off = 0;
  auto carve = [&](size_t bytes) -> char* {
    char* p = ws + off;
    off = (off + bytes + 255) & ~(size_t)255;
    return p;
  };
  const int nblk = (n1 + CHUNK - 1) / CHUNK;       // 1563
  float* max_iou   = (float*)carve((size_t)n1 * 4);
  int*   input_idx = (int*)  carve((size_t)n1 * 4);
  ull*   colpart   = (ull*)  carve((size_t)nblk * n2 * 8);
  int*   cnts_part = (int*)  carve((size_t)nblk * 24 * 4);
  int*   cnts      = (int*)  carve(32 * 4);
  ull*   colmax    = (ull*)  carve((size_t)MAXGT * 8);

  fused_iou<<<nblk, TPB, 0, stream>>>(boxes, gts, n1, n2, nblk,
                                      max_iou, input_idx, colpart,
                                      cnts_part, cnts, colmax, pos_noise, neg_noise);
  colreduce2<<<NRB, TPB, 0, stream>>>(colpart, n2, nblk, cnts_part, cnts, colmax);
  finalize2<<<2, TPF, 0, stream>>>(colmax, n1, n2, max_iou, input_idx,
                                   pos_noise, neg_noise, cnts, out);
}

// Round 11
// 130.664 us; speedup vs baseline: 1.1928x; 1.0333x over previous
//
#include <hip/hip_runtime.h>
#include <stdint.h>

#pragma clang fp contract(off)

typedef unsigned long long ull;

#define HIGHT 0.7f
#define LOWT  0.3f
#define KSEL  128
#define CAP   2048         // candidate buffer per mode
#define MAXGT 512
#define TPB   256
#define CHUNK 32           // proposals per fused_iou block (8 threads/proposal)
#define TJ    128          // j-tile for the shared IoU matrix
#define SMP   132          // pitch%32==4: write bank 4pi+q+8s (2-way), read bank 4s+jloc (free)
#define NLAD  7
#define NRB   96           // colreduce2 blocks (96 atomics/colmax address, fire-and-forget)

// counter layout (int cnts[32]):
// [0] posMask  [1] negMask(normal)  [2] notPos
// [3..9] pos ladder  [10..16] neg-normal ladder  [17..23] neg-fallback ladder
// [24] collect cnt pos  [25] collect cnt neg
__device__ __constant__ float LADV[NLAD] = {0.998f, 0.99f, 0.95f, 0.8f, 0.5f, 0.25f, 0.0625f};

// ---- bit-exact IoU (numpy fp32 op-for-op; no contraction; IEEE div) ----
__device__ __forceinline__ float iou_pair(float ax0, float ay0, float ax1, float ay1, float aarea,
                                          float bx0, float by0, float bx1, float by1, float barea){
#pragma clang fp contract(off)
  float x0 = fmaxf(ax0, bx0);
  float y0 = fmaxf(ay0, by0);
  float x1 = fminf(ax1, bx1);
  float y1 = fminf(ay1, by1);
  float dx = fmaxf(x1 - x0, 0.0f);
  float dy = fmaxf(y1 - y0, 0.0f);
  float inter = dx * dy;
  float uni = (aarea + barea) - inter;
  return inter / uni;   // keep IEEE div: surrogate compares flip near-tie argmax
}

// ---- K1: R4 structure with EIGHT independent row chains (was 4).
// fp32 IEEE-div chain ~28cy dependent latency; 8 chains cover it.
// Costs ~+30 VGPR -> 16 waves/CU (VGPR-capped) vs 20 (LDS-capped); R7 proved
// occupancy in this range is not the limiter — div-latency hiding is.
__global__ __launch_bounds__(TPB)
void fused_iou(const float4* __restrict__ boxes, const float4* __restrict__ gts,
               int n1, int n2, int nblk,
               float* __restrict__ max_iou, int* __restrict__ input_idx,
               ull* __restrict__ colpart, int* __restrict__ forced,
               int* __restrict__ cnts_part, int* __restrict__ cnts,
               ull* __restrict__ colmax,
               const float* __restrict__ pn, const float* __restrict__ nn)
{
#pragma clang fp contract(off)
  const int b = blockIdx.x, t = threadIdx.x;

  // distributed zeroing (consumed by later kernels; stream order suffices).
  // NOTE: colmax/cnts/forced MUST be re-zeroed every launch — the harness
  // re-poisons the workspace between runs (R6 failure: colmax zero dropped,
  // poison keys won the atomicMax).
  for (int x = b * TPB + t; x < n1; x += nblk * TPB) forced[x] = 0;
  if (b == 0){
    if (t < 32) cnts[t] = 0;
    for (int x = t; x < n2; x += TPB) colmax[x] = 0;  // key 0 loses to any real key
  }

  __shared__ float4 gc[MAXGT];
  __shared__ float  ga[MAXGT];
  __shared__ float  smat[CHUNK * SMP];   // 32 x 132 fp32 = 16.9 KB
  __shared__ float  sm[CHUNK];

  for (int j = t; j < n2; j += TPB){
    float4 g = gts[j];
    float hw = g.z * 0.5f, hh = g.w * 0.5f;
    gc[j] = make_float4(g.x - hw, g.y - hh, g.x + hw, g.y + hh);
    ga[j] = g.z * g.w;
  }
  __syncthreads();

  const int lo = b * CHUNK;
  int cr = n1 - lo; if (cr > CHUNK) cr = CHUNK; if (cr < 0) cr = 0;

  const int pi = t >> 3, q = t & 7;      // 8 threads per proposal
  const bool valid = (pi < cr);
  float px0 = 0, py0 = 0, px1 = 0, py1 = 0, pa = 0;
  if (valid){
    float4 pb = boxes[lo + pi];
    float hw = pb.z * 0.5f, hh = pb.w * 0.5f;
    px0 = pb.x - hw; py0 = pb.y - hh; px1 = pb.x + hw; py1 = pb.y + hh;
    pa = pb.z * pb.w;
  }
  // 8 independent row-argmax chains; chain k owns j ≡ q+8k (mod 64) —
  // disjoint j-sets, merged lexicographically (value desc, index asc) at end.
  float v0 = -1.0f, v1 = -1.0f, v2 = -1.0f, v3 = -1.0f;
  float v4 = -1.0f, v5 = -1.0f, v6 = -1.0f, v7 = -1.0f;
  int i0 = 0, i1 = 0, i2 = 0, i3 = 0, i4 = 0, i5 = 0, i6 = 0, i7 = 0;

  for (int tb = 0; tb < n2; tb += TJ){
    const int tn = min(TJ, n2 - tb);
    if (valid){
      if (tn == TJ){
        // full tile: 16 j's per thread as two fully-unrolled 8-chain groups.
        // smat write bank: (4pi + q + 8k + 64g)%32 == (4pi+q+8k)%32 -> 2-way
        // worst case (free), identical to the proven 4-chain pattern.
        #pragma unroll
        for (int g = 0; g < 2; ++g){
          const int jb = tb + q + g * 64;
          const int lb = q + g * 64;
          float4 G0 = gc[jb];      float A0 = ga[jb];
          float4 G1 = gc[jb + 8];  float A1 = ga[jb + 8];
          float4 G2 = gc[jb + 16]; float A2 = ga[jb + 16];
          float4 G3 = gc[jb + 24]; float A3 = ga[jb + 24];
          float4 G4 = gc[jb + 32]; float A4 = ga[jb + 32];
          float4 G5 = gc[jb + 40]; float A5 = ga[jb + 40];
          float4 G6 = gc[jb + 48]; float A6 = ga[jb + 48];
          float4 G7 = gc[jb + 56]; float A7 = ga[jb + 56];
          float u0 = iou_pair(px0, py0, px1, py1, pa, G0.x, G0.y, G0.z, G0.w, A0);
          float u1 = iou_pair(px0, py0, px1, py1, pa, G1.x, G1.y, G1.z, G1.w, A1);
          float u2 = iou_pair(px0, py0, px1, py1, pa, G2.x, G2.y, G2.z, G2.w, A2);
          float u3 = iou_pair(px0, py0, px1, py1, pa, G3.x, G3.y, G3.z, G3.w, A3);
          float u4 = iou_pair(px0, py0, px1, py1, pa, G4.x, G4.y, G4.z, G4.w, A4);
          float u5 = iou_pair(px0, py0, px1, py1, pa, G5.x, G5.y, G5.z, G5.w, A5);
          float u6 = iou_pair(px0, py0, px1, py1, pa, G6.x, G6.y, G6.z, G6.w, A6);
          float u7 = iou_pair(px0, py0, px1, py1, pa, G7.x, G7.y, G7.z, G7.w, A7);
          smat[pi * SMP + lb]      = u0;
          smat[pi * SMP + lb + 8]  = u1;
          smat[pi * SMP + lb + 16] = u2;
          smat[pi * SMP + lb + 24] = u3;
          smat[pi * SMP + lb + 32] = u4;
          smat[pi * SMP + lb + 40] = u5;
          smat[pi * SMP + lb + 48] = u6;
          smat[pi * SMP + lb + 56] = u7;
          if (u0 > v0){ v0 = u0; i0 = jb; }
          if (u1 > v1){ v1 = u1; i1 = jb + 8; }
          if (u2 > v2){ v2 = u2; i2 = jb + 16; }
          if (u3 > v3){ v3 = u3; i3 = jb + 24; }
          if (u4 > v4){ v4 = u4; i4 = jb + 32; }
          if (u5 > v5){ v5 = u5; i5 = jb + 40; }
          if (u6 > v6){ v6 = u6; i6 = jb + 48; }
          if (u7 > v7){ v7 = u7; i7 = jb + 56; }
        }
      } else {
        // ragged tail tile (not hit at n2=512; kept for generality)
        for (int j0 = tb + q; j0 < tb + tn; j0 += 8){
          float4 g0 = gc[j0]; float a0 = ga[j0];
          float u = iou_pair(px0, py0, px1, py1, pa, g0.x, g0.y, g0.z, g0.w, a0);
          smat[pi * SMP + (j0 - tb)] = u;
          if (u > v0){ v0 = u; i0 = j0; }
        }
      }
    }
    __syncthreads();
    // col reduce (R4-verbatim, proven): 2 threads/j, blocked p-chains of 16
    // (disjoint ascending -> merge lower-p on tie = global first occurrence).
    // Read bank (4p + jloc)%32 conflict-free; row-major colpart write coalesced.
    {
      const int jloc = t >> 1, half = t & 1;
      if (jloc < tn){
        float cv = -1.0f; int cp = 0;
        const int p0 = half * 16;
        const int p1 = min(p0 + 16, cr);
        for (int p = p0; p < p1; ++p){
          float v = smat[p * SMP + jloc];
          if (v > cv){ cv = v; cp = p; }
        }
        float ov = __shfl_xor(cv, 1, 64);
        int   op = __shfl_xor(cp, 1, 64);
        if (ov > cv || (ov == cv && op < cp)){ cv = ov; cp = op; }
        if (half == 0){
          // key: bits(nonneg IoU)<<32 | ~globalIdx -> max = best val, tie lowest idx
          colpart[(size_t)b * n2 + (tb + jloc)] =
            ((ull)__float_as_uint(cv) << 32) | (ull)(unsigned)~(unsigned)(lo + cp);
        }
      }
    }
    __syncthreads();
  }

  // merge the 8 chains (disjoint j-sets -> value-desc/index-asc merge is exact)
  float vA = v0; int jA = i0;
  if (v1 > vA || (v1 == vA && i1 < jA)){ vA = v1; jA = i1; }
  if (v2 > vA || (v2 == vA && i2 < jA)){ vA = v2; jA = i2; }
  if (v3 > vA || (v3 == vA && i3 < jA)){ vA = v3; jA = i3; }
  if (v4 > vA || (v4 == vA && i4 < jA)){ vA = v4; jA = i4; }
  if (v5 > vA || (v5 == vA && i5 < jA)){ vA = v5; jA = i5; }
  if (v6 > vA || (v6 == vA && i6 < jA)){ vA = v6; jA = i6; }
  if (v7 > vA || (v7 == vA && i7 < jA)){ vA = v7; jA = i7; }
  // merge the 8 octants of the row argmax (tie -> lower j)
  #pragma unroll
  for (int m = 1; m <= 4; m <<= 1){
    float ov = __shfl_xor(vA, m, 64);
    int   oj = __shfl_xor(jA, m, 64);
    if (ov > vA || (ov == vA && oj < jA)){ vA = ov; jA = oj; }
  }
  if (valid && q == 0){
    max_iou[lo + pi] = vA;
    input_idx[lo + pi] = jA;
    sm[pi] = vA;
  }
  __syncthreads();

  // provisional counts (ignore forced; forcefix corrects): wave 0, lane t = proposal
  if (t < 64){
    const bool vld = (t < cr);
    float m = vld ? sm[t] : -1.0f;
    bool pos = vld && (m > HIGHT);
    bool nm  = vld && (m < LOWT);
    bool np  = vld && !(m > HIGHT);
    float sp = pos ? pn[lo + t] : -1.0f;
    float sn = (nm || np) ? nn[lo + t] : -1.0f;
    int c[24];
    c[0] = __popcll(__ballot(pos));
    c[1] = __popcll(__ballot(nm));
    c[2] = __popcll(__ballot(np));
    #pragma unroll
    for (int k = 0; k < NLAD; ++k){
      float L = LADV[k];
      c[3 + k]  = __popcll(__ballot(pos && sp > L));
      c[10 + k] = __popcll(__ballot(nm  && sn > L));
      c[17 + k] = __popcll(__ballot(np  && sn > L));
    }
    if (t == 0){
      #pragma unroll
      for (int k = 0; k < 24; ++k) cnts_part[b * 24 + k] = c[k];
    }
  }
}

// ---- K2 (R4-exact, proven): fence-free row-sliced column reduction + cnts
// reduce. Thread t owns columns t and t+256; each block scans rows b, b+NRB,
// ... reading full 4KB rows coalesced. One fire-and-forget atomicMax per
// column per block (NRB per address, no barrier behind them, no fences).
__global__ __launch_bounds__(TPB)
void colreduce2(const ull* __restrict__ colpart, int n2, int nblk,
                const int* __restrict__ cnts_part,
                int* __restrict__ cnts, ull* __restrict__ colmax)
{
  const int t = threadIdx.x, b = blockIdx.x;
  ull m0 = 0, m1 = 0;
  const int c0 = t, c1 = t + TPB;          // n2 = 512 = 2*TPB
  for (int x = b; x < nblk; x += NRB){
    const ull* row = colpart + (size_t)x * n2;
    ull v0 = row[c0];
    ull v1 = (c1 < n2) ? row[c1] : 0;
    if (v0 > m0) m0 = v0;
    if (v1 > m1) m1 = v1;
  }
  if (c0 < n2 && m0) atomicMax(&colmax[c0], m0);
  if (c1 < n2 && m1) atomicMax(&colmax[c1], m1);

  // provisional counter reduction (24 columns)
  if (t < 24){
    int s = 0;
    for (int x = b; x < nblk; x += NRB) s += cnts_part[x * 24 + t];
    if (s) atomicAdd(&cnts[t], s);
  }
}

// ---- K3 (proven): forced scatter + exact counter corrections (1 block).
// Visibility of colmax/cnts guaranteed by the kernel boundary (no fences —
// R9 lesson: a device-scope fence in a wide grid costs ~50us).
__global__ __launch_bounds__(512)
void forcefix(const ull* __restrict__ colmax, int n1, int n2,
              const float* __restrict__ max_iou,
              const float* __restrict__ pn, const float* __restrict__ nn,
              int* __restrict__ forced, int* __restrict__ cnts)
{
  const int t = threadIdx.x;
  if (t >= n2) return;
  ull key = colmax[t];
  unsigned idx = ~(unsigned)(key & 0xFFFFFFFFull);
  if (idx >= (unsigned)n1) return;
  int old = atomicExch(&forced[idx], 1);      // dedupe: first claimer corrects
  if (old != 0) return;
  float m2 = max_iou[idx];
  if (m2 > HIGHT) return;                     // forcing flips this row to pos
  float sp = pn[idx];
  float sn = nn[idx];
  atomicAdd(&cnts[0], 1);
  atomicAdd(&cnts[2], -1);
  #pragma unroll
  for (int k = 0; k < NLAD; ++k){
    float L = LADV[k];
    if (sp > L) atomicAdd(&cnts[3 + k], 1);
    if (sn > L) atomicAdd(&cnts[17 + k], -1);
  }
  if (m2 < LOWT){
    atomicAdd(&cnts[1], -1);
    #pragma unroll
    for (int k = 0; k < NLAD; ++k)
      if (sn > LADV[k]) atomicAdd(&cnts[10 + k], -1);
  }
}

// ---- tau: LARGEST ladder level with >= KSEL survivors (tight superset).
// Exact: the top-KSEL by noise all score > that level; adjacent ladder
// fractions differ <=5x so survivors at the chosen level stay << CAP.
// If no level qualifies (totM < ~KSEL) tau=-1 collects all masked.
__device__ __forceinline__ float pick_tau2(const int* lad){
  for (int k = 0; k < NLAD; ++k)
    if (lad[k] >= KSEL) return LADV[k];
  return -1.0f;
}

// ---- K4 (R7-proven): grid-wide collect into global cand buffers ----
__global__ __launch_bounds__(TPB)
void collect_kernel(const float* __restrict__ max_iou, const int* __restrict__ forced,
                    const float* __restrict__ pn, const float* __restrict__ nn,
                    int n1, int* __restrict__ cnts, ull* __restrict__ cand)
{
  __shared__ int s_c[24];
  const int t = threadIdx.x;
  if (t < 24) s_c[t] = cnts[t];
  __syncthreads();
  const bool fb = (s_c[1] == 0);                 // no negatives -> complement of pos
  const int totP = s_c[0];
  const int totN = fb ? s_c[2] : s_c[1];
  const float tauP = pick_tau2(&s_c[3]);
  const float tauN = pick_tau2(fb ? &s_c[17] : &s_c[10]);

  const int i = blockIdx.x * TPB + t;
  if (i >= n1) return;
  float m = max_iou[i];
  bool f = forced[i] != 0;
  bool pos = (m > HIGHT) || f;
  // Key: (bits(score)+1)<<32 | ~i (score in [0,1) -> bits monotone; +1 so the
  // fill key (k32=0) loses to a real 0.0 score).
  if (pos){
    float sc = pn[i];
    if (sc > tauP){
      int p = atomicAdd(&cnts[24], 1);
      if (p < CAP) cand[p] = ((ull)(__float_as_uint(sc) + 1u) << 32) | (ull)(unsigned)~(unsigned)i;
    }
  } else if (totP < KSEL && i < 2 * KSEL){
    // ref top_k fills with -1-scored entries in ascending index; all needed
    // fills have index < 2*KSEL
    int p = atomicAdd(&cnts[24], 1);
    if (p < CAP) cand[p] = (ull)(unsigned)~(unsigned)i;
  }
  bool seln = fb ? (!pos) : ((m < LOWT) && !f);
  if (seln){
    float sc = nn[i];
    if (sc > tauN){
      int p = atomicAdd(&cnts[25], 1);
      if (p < CAP) cand[CAP + p] = ((ull)(__float_as_uint(sc) + 1u) << 32) | (ull)(unsigned)~(unsigned)i;
    }
  } else if (totN < KSEL && i < 2 * KSEL){
    int p = atomicAdd(&cnts[25], 1);
    if (p < CAP) cand[CAP + p] = (ull)(unsigned)~(unsigned)i;
  }
}

// ---- K5 (R7-proven): exact rank-select of top-128 per mode ----
__global__ __launch_bounds__(1024)
void select_kernel(const ull* __restrict__ cand, const int* __restrict__ cnts,
                   const int* __restrict__ input_idx, int* __restrict__ out)
{
  const int t = threadIdx.x;
  const bool isPos = (blockIdx.x == 0);
  __shared__ ull keys[CAP];
  int n = cnts[isPos ? 24 : 25]; if (n > CAP) n = CAP;
  for (int x = t; x < n; x += 1024)
    keys[x] = cand[(isPos ? 0 : CAP) + x];
  __syncthreads();
  // fixed register slots (compile-time indices); sentinel ~0ull never selected
  ull mk[2]; int mr[2];
  #pragma unroll
  for (int e = 0; e < 2; ++e){
    int x = t + e * 1024;
    mk[e] = (x < n) ? keys[x] : ~0ull;
    mr[e] = 0;
  }
  for (int o = 0; o < n; ++o){
    ull ko = keys[o];                             // uniform addr -> LDS broadcast
    #pragma unroll
    for (int e = 0; e < 2; ++e) mr[e] += (ko > mk[e]);
  }
  #pragma unroll
  for (int e = 0; e < 2; ++e){
    int x = t + e * 1024;
    if (x < n && mr[e] < KSEL){
      unsigned idx = ~(unsigned)(mk[e] & 0xFFFFFFFFull);
      if (isPos){ out[mr[e]] = (int)idx; out[KSEL + mr[e]] = input_idx[idx]; }
      else        out[2 * KSEL + mr[e]] = (int)idx;
    }
  }
}

extern "C" void kernel_launch(void* const* d_in, const int* in_sizes, int n_in,
                              void* d_out, int out_size, void* d_ws, size_t ws_size,
                              hipStream_t stream){
  const float4* boxes = (const float4*)d_in[0];
  const float4* gts   = (const float4*)d_in[1];
  const float* pos_noise = (const float*)d_in[2];
  const float* neg_noise = (const float*)d_in[3];
  const int n1 = in_sizes[0] / 4;
  const int n2 = in_sizes[1] / 4;
  int* out = (int*)d_out;

  char* ws = (char*)d_ws;
  size_t off = 0;
  auto carve = [&](size_t bytes) -> char* {
    char* p = ws + off;
    off = (off + bytes + 255) & ~(size_t)255;
    return p;
  };
  const int nblk = (n1 + CHUNK - 1) / CHUNK;       // 1563
  float* max_iou   = (float*)carve((size_t)n1 * 4);
  int*   input_idx = (int*)  carve((size_t)n1 * 4);
  ull*   colpart   = (ull*)  carve((size_t)nblk * n2 * 8);
  int*   forced    = (int*)  carve((size_t)n1 * 4);
  int*   cnts_part = (int*)  carve((size_t)nblk * 24 * 4);
  int*   cnts      = (int*)  carve(32 * 4);
  ull*   colmax    = (ull*)  carve((size_t)MAXGT * 8);
  ull*   cand      = (ull*)  carve((size_t)2 * CAP * 8);

  const int gb = (n1 + TPB - 1) / TPB;             // 196
  fused_iou<<<nblk, TPB, 0, stream>>>(boxes, gts, n1, n2, nblk,
                                      max_iou, input_idx, colpart, forced,
                                      cnts_part, cnts, colmax, pos_noise, neg_noise);
  colreduce2<<<NRB, TPB, 0, stream>>>(colpart, n2, nblk, cnts_part, cnts, colmax);
  forcefix<<<1, 512, 0, stream>>>(colmax, n1, n2, max_iou,
                                  pos_noise, neg_noise, forced, cnts);
  collect_kernel<<<gb, TPB, 0, stream>>>(max_iou, forced, pos_noise, neg_noise,
                                         n1, cnts, cand);
  select_kernel<<<2, 1024, 0, stream>>>(cand, cnts, input_idx, out);
}